// Round 1
// baseline (286.086 us; speedup 1.0000x reference)
//
#include <hip/hip_runtime.h>
#include <math.h>

#define SMOOTH_F 1e-5f
#define ALPHA_F 0.25f

constexpr int Bn = 8;
constexpr int NCn = 1000;
constexpr int Cn = 19;
constexpr int HWn = 512 * 512;      // 262144
constexpr int Dn = 768;
constexpr int BC = Bn * Cn;         // 152

constexpr int TPB = 256;
constexpr int CHUNK = 2048;                    // pixels per block
constexpr int CHUNKS_PER_B = HWn / CHUNK;      // 128
constexpr int SEG_BLOCKS = Bn * CHUNKS_PER_B;  // 1024
constexpr int GROUPS = CHUNK / (TPB * 4);      // 2 groups of 4 pixels/thread

// ws float-slot layout
constexpr int WS_INTER = 0;          // [0,152)   sum(pred * onehot) per (b,c)
constexpr int WS_PRED  = BC;         // [152,304) sum(pred) per (b,c)
constexpr int WS_CNT   = 2 * BC;     // [304,456) sum(onehot) per (b,c)
constexpr int WS_FOCAL = 3 * BC;     // 456 focal numerator sum
constexpr int WS_CE    = 3 * BC + 1; // 457
constexpr int WS_MB    = 3 * BC + 2; // 458
constexpr int WS_N     = 3 * BC + 3; // 459

__device__ __forceinline__ float wave_sum(float v) {
#pragma unroll
  for (int off = 32; off > 0; off >>= 1) v += __shfl_down(v, off, 64);
  return v;
}
__device__ __forceinline__ float wave_max(float v) {
#pragma unroll
  for (int off = 32; off > 0; off >>= 1) v = fmaxf(v, __shfl_down(v, off, 64));
  return v;
}

__global__ __launch_bounds__(256) void k_zero(float* __restrict__ ws) {
  int t = blockIdx.x * blockDim.x + threadIdx.x;
  if (t < WS_N) ws[t] = 0.0f;
}

// block 0: cross-entropy over logits[8,1000]; block 1: modal balance
__global__ __launch_bounds__(256) void k_small(
    const float* __restrict__ logits, const int* __restrict__ label,
    const float* __restrict__ vf, const float* __restrict__ tf,
    const float* __restrict__ mmask, const int* __restrict__ epoch,
    float* __restrict__ ws) {
  __shared__ float sA[4];
  __shared__ float sBv[4];
  __shared__ float nv[Bn];
  __shared__ float nt[Bn];
  __shared__ float s3[3][4];
  const int tid = threadIdx.x;
  const int wid = tid >> 6, lane = tid & 63;

  if (blockIdx.x == 0) {
    // ---- cross entropy ----
    float acc = 0.0f;
    for (int b = 0; b < Bn; ++b) {
      const float* row = logits + b * NCn;
      float lm = -INFINITY;
      for (int j = tid; j < NCn; j += TPB) lm = fmaxf(lm, row[j]);
      lm = wave_max(lm);
      if (lane == 0) sA[wid] = lm;
      __syncthreads();
      float bm = fmaxf(fmaxf(sA[0], sA[1]), fmaxf(sA[2], sA[3]));
      __syncthreads();
      float ls = 0.0f;
      for (int j = tid; j < NCn; j += TPB) ls += expf(row[j] - bm);
      ls = wave_sum(ls);
      if (lane == 0) sA[wid] = ls;
      __syncthreads();
      if (tid == 0) {
        float lse = bm + logf(sA[0] + sA[1] + sA[2] + sA[3]);
        acc += row[label[b]] - lse;
      }
      __syncthreads();
    }
    if (tid == 0) ws[WS_CE] = -(acc / (float)Bn);
  } else {
    // ---- modal balance ----
    // phase A: row norms of vision/text feats
    for (int b = 0; b < Bn; ++b) {
      float sv = 0.0f, st = 0.0f;
      for (int j = tid; j < Dn; j += TPB) {
        float a = vf[b * Dn + j];
        float c = tf[b * Dn + j];
        sv += a * a;
        st += c * c;
      }
      sv = wave_sum(sv);
      st = wave_sum(st);
      if (lane == 0) { sA[wid] = sv; sBv[wid] = st; }
      __syncthreads();
      if (tid == 0) {
        nv[b] = sqrtf(sA[0] + sA[1] + sA[2] + sA[3]);
        nt[b] = sqrtf(sBv[0] + sBv[1] + sBv[2] + sBv[3]);
      }
      __syncthreads();
    }
    // phase B: per-column variance across batch + cross-cosine
    float colv = 0.0f, colt = 0.0f, cross = 0.0f;
    for (int j = tid; j < Dn; j += TPB) {
      float sv = 0.0f, ssv = 0.0f, stt = 0.0f, sst = 0.0f, cr = 0.0f;
      for (int b = 0; b < Bn; ++b) {
        float vn = vf[b * Dn + j] / nv[b];
        float tn = tf[b * Dn + j] / nt[b];
        sv += vn; ssv += vn * vn;
        stt += tn; sst += tn * tn;
        cr += vn * tn;
      }
      colv += ssv - sv * sv * 0.125f;
      colt += sst - stt * stt * 0.125f;
      cross += cr;
    }
    colv = wave_sum(colv);
    colt = wave_sum(colt);
    cross = wave_sum(cross);
    if (lane == 0) { s3[0][wid] = colv; s3[1][wid] = colt; s3[2][wid] = cross; }
    __syncthreads();
    if (tid == 0) {
      float cv = s3[0][0] + s3[0][1] + s3[0][2] + s3[0][3];
      float ct = s3[1][0] + s3[1][1] + s3[1][2] + s3[1][3];
      float cr = s3[2][0] + s3[2][1] + s3[2][2] + s3[2][3];
      float v_cons = cv / (float)(Bn * Dn);
      float t_cons = ct / (float)(Bn * Dn);
      float crossv = 1.0f - cr * 0.125f;
      float beta = 0.5f * powf(0.99f, (float)epoch[0]);
      float mm0 = 0.0f, mm1 = 0.0f;
      for (int b = 0; b < Bn; ++b) { mm0 += mmask[b * 2]; mm1 += mmask[b * 2 + 1]; }
      mm0 *= 0.125f; mm1 *= 0.125f;
      ws[WS_MB] = (1.0f - beta) * v_cons * mm0 + beta * t_cons * mm1 + crossv;
    }
  }
}

// fused dice-sums + focal over seg_mask [8,19,512,512], seg_gt [8,512,512]
__global__ __launch_bounds__(TPB) void k_seg(
    const float* __restrict__ pred, const int* __restrict__ gt,
    float* __restrict__ ws) {
  __shared__ float s_inter[Cn];
  __shared__ float s_count[Cn];
  __shared__ float s_pred[Cn];
  __shared__ float s_red[4];

  const int tid = threadIdx.x;
  const int wid = tid >> 6, lane = tid & 63;
  const int b = blockIdx.x / CHUNKS_PER_B;
  const int chunk = blockIdx.x % CHUNKS_PER_B;

  if (tid < Cn) { s_inter[tid] = 0.0f; s_count[tid] = 0.0f; s_pred[tid] = 0.0f; }
  __syncthreads();

  const float4* predb = (const float4*)(pred + (size_t)b * Cn * HWn);
  const int4* gtb = (const int4*)(gt + (size_t)b * HWn);
  const int base4 = chunk * (CHUNK / 4);

  float psum[Cn];
#pragma unroll
  for (int c = 0; c < Cn; ++c) psum[c] = 0.0f;
  float focal = 0.0f;

#pragma unroll 1
  for (int g = 0; g < GROUPS; ++g) {
    const int idx4 = base4 + g * TPB + tid;
    const int4 t4 = gtb[idx4];
    float4 xs[Cn];
#pragma unroll
    for (int c = 0; c < Cn; ++c)
      xs[c] = predb[(size_t)c * (HWn / 4) + idx4];

    float4 m = xs[0];
#pragma unroll
    for (int c = 1; c < Cn; ++c) {
      m.x = fmaxf(m.x, xs[c].x); m.y = fmaxf(m.y, xs[c].y);
      m.z = fmaxf(m.z, xs[c].z); m.w = fmaxf(m.w, xs[c].w);
    }
    float4 se = make_float4(0.f, 0.f, 0.f, 0.f);
    float4 xt = make_float4(0.f, 0.f, 0.f, 0.f);
#pragma unroll
    for (int c = 0; c < Cn; ++c) {
      se.x += expf(xs[c].x - m.x); se.y += expf(xs[c].y - m.y);
      se.z += expf(xs[c].z - m.z); se.w += expf(xs[c].w - m.w);
      if (t4.x == c) xt.x = xs[c].x;
      if (t4.y == c) xt.y = xs[c].y;
      if (t4.z == c) xt.z = xs[c].z;
      if (t4.w == c) xt.w = xs[c].w;
      psum[c] += (xs[c].x + xs[c].y) + (xs[c].z + xs[c].w);
    }
    float4 lse;
    lse.x = m.x + logf(se.x); lse.y = m.y + logf(se.y);
    lse.z = m.z + logf(se.z); lse.w = m.w + logf(se.w);

    // focal: alpha * (1-p)^2 * (-logp_t)
    {
      float lpt, p, om;
      lpt = xt.x - lse.x; p = expf(lpt); om = 1.0f - p; focal += om * om * (-lpt);
      lpt = xt.y - lse.y; p = expf(lpt); om = 1.0f - p; focal += om * om * (-lpt);
      lpt = xt.z - lse.z; p = expf(lpt); om = 1.0f - p; focal += om * om * (-lpt);
      lpt = xt.w - lse.w; p = expf(lpt); om = 1.0f - p; focal += om * om * (-lpt);
    }
    // dice: inter and onehot-count via LDS atomics
    atomicAdd(&s_inter[t4.x], xt.x);
    atomicAdd(&s_inter[t4.y], xt.y);
    atomicAdd(&s_inter[t4.z], xt.z);
    atomicAdd(&s_inter[t4.w], xt.w);
    atomicAdd(&s_count[t4.x], 1.0f);
    atomicAdd(&s_count[t4.y], 1.0f);
    atomicAdd(&s_count[t4.z], 1.0f);
    atomicAdd(&s_count[t4.w], 1.0f);
  }

  focal *= ALPHA_F;
  float fw = wave_sum(focal);
  if (lane == 0) s_red[wid] = fw;
#pragma unroll
  for (int c = 0; c < Cn; ++c) {
    float v = wave_sum(psum[c]);
    if (lane == 0) atomicAdd(&s_pred[c], v);
  }
  __syncthreads();

  if (tid < Cn) {
    atomicAdd(&ws[WS_INTER + b * Cn + tid], s_inter[tid]);
    atomicAdd(&ws[WS_PRED + b * Cn + tid], s_pred[tid]);
    atomicAdd(&ws[WS_CNT + b * Cn + tid], s_count[tid]);
  }
  if (tid == 0)
    atomicAdd(&ws[WS_FOCAL], s_red[0] + s_red[1] + s_red[2] + s_red[3]);
}

__global__ __launch_bounds__(256) void k_final(
    const float* __restrict__ ws, float* __restrict__ out) {
  __shared__ float sA[4];
  const int tid = threadIdx.x;
  const int wid = tid >> 6, lane = tid & 63;
  float v = 0.0f;
  if (tid < BC) {
    float inter = ws[WS_INTER + tid];
    float ps = ws[WS_PRED + tid];
    float cnt = ws[WS_CNT + tid];
    float dice = (2.0f * inter + SMOOTH_F) / (ps + cnt + SMOOTH_F);
    v = 1.0f - dice;
  }
  v = wave_sum(v);
  if (lane == 0) sA[wid] = v;
  __syncthreads();
  if (tid == 0) {
    float dice_mean = (sA[0] + sA[1] + sA[2] + sA[3]) / (float)BC;
    float focal_mean = ws[WS_FOCAL] / (float)(Bn * HWn);
    float seg = dice_mean + focal_mean;
    out[0] = ws[WS_CE] + 0.3f * ws[WS_MB] + 0.5f * seg;
  }
}

extern "C" void kernel_launch(void* const* d_in, const int* in_sizes, int n_in,
                              void* d_out, int out_size, void* d_ws, size_t ws_size,
                              hipStream_t stream) {
  const float* logits = (const float*)d_in[0];
  const int* label    = (const int*)d_in[1];
  const float* vf     = (const float*)d_in[2];
  const float* tf     = (const float*)d_in[3];
  const float* mmask  = (const float*)d_in[4];
  const float* seg    = (const float*)d_in[5];
  const int* gt       = (const int*)d_in[6];
  const int* epoch    = (const int*)d_in[7];
  float* out = (float*)d_out;
  float* ws = (float*)d_ws;

  hipLaunchKernelGGL(k_zero, dim3(2), dim3(256), 0, stream, ws);
  hipLaunchKernelGGL(k_small, dim3(2), dim3(256), 0, stream,
                     logits, label, vf, tf, mmask, epoch, ws);
  hipLaunchKernelGGL(k_seg, dim3(SEG_BLOCKS), dim3(TPB), 0, stream, seg, gt, ws);
  hipLaunchKernelGGL(k_final, dim3(1), dim3(256), 0, stream, ws, out);
}